// Round 1
// baseline (2435.159 us; speedup 1.0000x reference)
//
#include <hip/hip_runtime.h>
#include <hip/hip_fp16.h>

// Problem constants
#define BB  64
#define CIN 256
#define HH  256
#define TT  512
#define G4  1024   // 4*H

typedef _Float16 half2_t __attribute__((ext_vector_type(2)));

__device__ __forceinline__ float dot2f(float wa, float hb, float acc) {
  half2_t a = __builtin_bit_cast(half2_t, wa);
  half2_t b = __builtin_bit_cast(half2_t, hb);
#if __has_builtin(__builtin_amdgcn_fdot2)
  return __builtin_amdgcn_fdot2(a, b, acc, false);
#else
  return acc + (float)a.x * (float)b.x + (float)a.y * (float)b.y;
#endif
}

__device__ __forceinline__ float dot8(float4 w, float4 h, float acc) {
  acc = dot2f(w.x, h.x, acc);
  acc = dot2f(w.y, h.y, acc);
  acc = dot2f(w.z, h.z, acc);
  acc = dot2f(w.w, h.w, acc);
  return acc;
}

__device__ __forceinline__ float fast_rcp(float x) { return __builtin_amdgcn_rcpf(x); }
// sigmoid(x) = 1/(1+exp(-x)); exp(-x) = exp2(-x*log2e)
__device__ __forceinline__ float fast_sig(float x) {
  return fast_rcp(1.0f + exp2f(-1.4426950408889634f * x));
}
// tanh(x) = 1 - 2/(1+exp(2x)); exp(2x) = exp2(x*2*log2e)
__device__ __forceinline__ float fast_tanh(float x) {
  return 1.0f - 2.0f * fast_rcp(1.0f + exp2f(2.8853900817779268f * x));
}

// ---------------------------------------------------------------------------
// Kernel 0: W_hh (B,H,4H) fp32  ->  Wc (B,4H,H) f16  (column-major per gate col)
// so the recurrence thread j reads its 256-long k-column contiguously.
// ---------------------------------------------------------------------------
__global__ __launch_bounds__(256) void transpose_whh(const float* __restrict__ W,
                                                     __half* __restrict__ Wc) {
  __shared__ __half tile[32][33];
  int b  = blockIdx.z;
  int j0 = blockIdx.x * 32;   // gate-col tile
  int k0 = blockIdx.y * 32;   // hidden-k tile
  int tx = threadIdx.x;       // 0..31
  int ty = threadIdx.y;       // 0..7
  const float* Wb = W + (size_t)b * HH * G4;
#pragma unroll
  for (int r = 0; r < 32; r += 8)
    tile[ty + r][tx] = __float2half(Wb[(size_t)(k0 + ty + r) * G4 + j0 + tx]);
  __syncthreads();
  __half* out = Wc + (size_t)b * G4 * HH;
#pragma unroll
  for (int r = 0; r < 32; r += 8)
    out[(size_t)(j0 + ty + r) * HH + k0 + tx] = tile[tx][ty + r];
}

// ---------------------------------------------------------------------------
// Kernel 1: WX[b][t][j] = sum_i x[b][i][t] * W_ih[b][i][j] + b_h[b][j], f16 out.
// fp32 LDS-tiled GEMM, 64x64 tile, 4x4 micro-tile, K-chunk 16.
// ---------------------------------------------------------------------------
__global__ __launch_bounds__(256) void gemm_wx(const float* __restrict__ X,
                                               const float* __restrict__ Wih,
                                               const float* __restrict__ bh,
                                               __half* __restrict__ WX) {
  __shared__ float As[16][64];  // As[k][t]
  __shared__ float Bs[16][64];  // Bs[k][j]
  int b  = blockIdx.z;
  int t0 = blockIdx.y * 64;
  int j0 = blockIdx.x * 64;
  int tid = threadIdx.x;
  int tx = tid & 15;   // j group: 4 cols
  int ty = tid >> 4;   // t group: 4 rows
  const float* Xb = X   + (size_t)b * CIN * TT;
  const float* Wb = Wih + (size_t)b * CIN * G4;
  float acc[4][4] = {};
  for (int i0 = 0; i0 < CIN; i0 += 16) {
#pragma unroll
    for (int q = 0; q < 4; ++q) {
      int lin = tid + q * 256;       // 0..1023
      int k  = lin >> 6;             // 0..15
      int tt = lin & 63;             // 0..63
      As[k][tt] = Xb[(size_t)(i0 + k) * TT + t0 + tt];
      Bs[k][tt] = Wb[(size_t)(i0 + k) * G4 + j0 + tt];
    }
    __syncthreads();
#pragma unroll
    for (int k = 0; k < 16; ++k) {
      float4 av = *(const float4*)&As[k][ty * 4];
      float4 bv = *(const float4*)&Bs[k][tx * 4];
      float a[4] = {av.x, av.y, av.z, av.w};
      float c[4] = {bv.x, bv.y, bv.z, bv.w};
#pragma unroll
      for (int r = 0; r < 4; ++r)
#pragma unroll
        for (int cc = 0; cc < 4; ++cc)
          acc[r][cc] = fmaf(a[r], c[cc], acc[r][cc]);
    }
    __syncthreads();
  }
  const float* bias = bh + (size_t)b * G4;
  float bcol[4];
#pragma unroll
  for (int cc = 0; cc < 4; ++cc) bcol[cc] = bias[j0 + tx * 4 + cc];
#pragma unroll
  for (int r = 0; r < 4; ++r) {
    int t = t0 + ty * 4 + r;
    __half* dst = WX + ((size_t)b * TT + t) * G4 + j0 + tx * 4;
    __half2 p0 = __floats2half2_rn(acc[r][0] + bcol[0], acc[r][1] + bcol[1]);
    __half2 p1 = __floats2half2_rn(acc[r][2] + bcol[2], acc[r][3] + bcol[3]);
    float2 st;
    st.x = __builtin_bit_cast(float, p0);
    st.y = __builtin_bit_cast(float, p1);
    *(float2*)dst = st;
  }
}

// ---------------------------------------------------------------------------
// Kernel 2: sequential recurrence. One workgroup per batch, 1024 threads.
// Thread j owns gate column j: wh[j] = dot(h, Wc[b][j][:]) via v_dot2_f32_f16.
// h broadcast through LDS (f16), gates exchanged through LDS (f32).
// ---------------------------------------------------------------------------
__global__ __launch_bounds__(1024) void lstm_rec(const __half* __restrict__ Wc,
                                                 const __half* __restrict__ WX,
                                                 const float* __restrict__ h0,
                                                 const float* __restrict__ c0,
                                                 float* __restrict__ out) {
  __shared__ float4 h4[32];       // 256 f16 = 512 B
  __shared__ float gates[G4];
  int b = blockIdx.x;
  int j = threadIdx.x;
  float c_reg = 0.0f;
  if (j < HH) {
    c_reg = c0[b * HH + j];
    ((__half*)h4)[j] = __float2half(h0[b * HH + j]);
  }
  __syncthreads();
  const float4* wcol = (const float4*)(Wc + ((size_t)b * G4 + j) * HH);  // 32 x 16B
  const __half* wxp  = WX + (size_t)b * TT * G4 + j;
  float* outb = out + (size_t)b * HH * TT;
  for (int t = 0; t < TT; ++t) {
    float a0 = 0.f, a1 = 0.f, a2 = 0.f, a3 = 0.f;
#pragma unroll
    for (int m = 0; m < 32; m += 4) {
      float4 w0 = wcol[m + 0], w1 = wcol[m + 1], w2 = wcol[m + 2], w3 = wcol[m + 3];
      float4 x0 = h4[m + 0],  x1 = h4[m + 1],  x2 = h4[m + 2],  x3 = h4[m + 3];
      a0 = dot8(w0, x0, a0);
      a1 = dot8(w1, x1, a1);
      a2 = dot8(w2, x2, a2);
      a3 = dot8(w3, x3, a3);
    }
    float z = (a0 + a1) + (a2 + a3) + __half2float(wxp[(size_t)t * G4]);
    gates[j] = fast_tanh(z);
    __syncthreads();
    if (j < HH) {
      float ig = gates[j];
      float fg = gates[HH + j];
      float gg = gates[2 * HH + j];
      float og = gates[3 * HH + j];
      c_reg = c_reg * fast_sig(fg) + fast_sig(ig) * fast_tanh(gg);
      float hv = fast_sig(og) * fast_tanh(c_reg);
      outb[(size_t)j * TT + t] = hv;          // h_out[b][j][t]
      ((__half*)h4)[j] = __float2half(hv);    // broadcast for next step
    }
    __syncthreads();
  }
  if (j < HH) out[(size_t)BB * HH * TT + b * HH + j] = c_reg;  // c_f
}

// ---------------------------------------------------------------------------
extern "C" void kernel_launch(void* const* d_in, const int* in_sizes, int n_in,
                              void* d_out, int out_size, void* d_ws, size_t ws_size,
                              hipStream_t stream) {
  const float* x    = (const float*)d_in[0];
  const float* h0   = (const float*)d_in[1];
  const float* c0   = (const float*)d_in[2];
  const float* W_ih = (const float*)d_in[3];
  const float* W_hh = (const float*)d_in[4];
  const float* b_h  = (const float*)d_in[5];
  float* out = (float*)d_out;

  // Workspace layout:
  //   [0, 33554432)            Wc  : f16 W_hh transposed, (B,4H,H)
  //   [33554432, 100663296)    WXh : f16 precomputed wx+bias, (B,T,4H)
  __half* Wc  = (__half*)d_ws;
  __half* WXh = (__half*)((char*)d_ws + (size_t)33554432);

  transpose_whh<<<dim3(G4 / 32, HH / 32, BB), dim3(32, 8), 0, stream>>>(W_hh, Wc);
  gemm_wx<<<dim3(G4 / 64, TT / 64, BB), dim3(256), 0, stream>>>(x, W_ih, b_h, WXh);
  lstm_rec<<<dim3(BB), dim3(1024), 0, stream>>>(Wc, WXh, h0, c0, out);
}